// Round 12
// baseline (284.880 us; speedup 1.0000x reference)
//
#include <hip/hip_runtime.h>
#include <hip/hip_bf16.h>

#define K1 195
#define K1P 224
#define K2 131
#define K2P 160
#define OC 256
#define BM 32
#define S1 232   // LDS row stride A1 (bf16): 464 B; rows 16B-aligned (232=29*8)
#define S2 168   // LDS row stride A2 (bf16): 336 B; rows 16B-aligned (168=21*8)
#define THREADS 512

typedef __attribute__((ext_vector_type(4))) float f32x4;
typedef __attribute__((ext_vector_type(8))) short bf16x8;
typedef __attribute__((ext_vector_type(4))) short bf16x4;

__device__ __forceinline__ short f2b(float x) {
    __hip_bfloat16 h = __float2bfloat16(x);
    return *reinterpret_cast<short*>(&h);
}

__global__ void prep_weights_v12(const float* __restrict__ Wc, const float* __restrict__ Wa,
                                 __hip_bfloat16* __restrict__ WcP, __hip_bfloat16* __restrict__ WaP) {
    int t = blockIdx.x * blockDim.x + threadIdx.x;
    const int total1 = OC * K1P;
    const int total2 = OC * K2P;
    if (t < total1) {
        int oc = t / K1P, k = t - oc * K1P;
        float v = (k < K1) ? Wc[oc * K1 + k] : 0.0f;
        WcP[t] = __float2bfloat16(v);
    } else if (t < total1 + total2) {
        int u = t - total1;
        int oc = u / K2P, k = u - oc * K2P;
        float v = (k < K2) ? Wa[oc * K2 + k] : 0.0f;
        WaP[u] = __float2bfloat16(v);
    }
}

__global__ __launch_bounds__(THREADS) void fused_mesh_v12(
        const float* __restrict__ spatial,
        const float* __restrict__ structural,
        const int* __restrict__ neighbour,
        const __hip_bfloat16* __restrict__ WcP,
        const float* __restrict__ bc,
        const __hip_bfloat16* __restrict__ WaP,
        const float* __restrict__ ba,
        float* __restrict__ out1,
        float* __restrict__ out2,
        int n) {
    __shared__ __hip_bfloat16 A1[BM][S1];
    __shared__ __hip_bfloat16 A2[BM][S2];
    __shared__ int nidx[BM * 3];

    const int t = threadIdx.x;
    const int r0 = blockIdx.x * BM;

    // ---- stage neighbour indices ----
    if (t < BM * 3) {
        size_t gi = (size_t)r0 * 3 + t;
        nidx[t] = (gi < (size_t)n * 3) ? neighbour[gi] : 0;
    }

    // ---- zero-pad K tails ----
    for (int e = t; e < BM * (K1P - K1); e += THREADS) {
        int r = e / (K1P - K1);
        int k = K1 + (e - r * (K1P - K1));
        A1[r][k] = __float2bfloat16(0.0f);
    }
    for (int e = t; e < BM * (K2P - K2); e += THREADS) {
        int r = e / (K2P - K2);
        int k = K2 + (e - r * (K2P - K2));
        A2[r][k] = __float2bfloat16(0.0f);
    }

    // ---- spatial -> A1[:, 0:64] : 16 threads/row, 4 floats/thread ----
    {
        int r  = t >> 4;              // 0..31
        int c0 = (t & 15) * 4;        // 0,4,..,60
        int rr = min(r0 + r, n - 1);
        f32x4 v = *(const f32x4*)(spatial + (size_t)rr * 64 + c0);
        bf16x4 o;
        #pragma unroll
        for (int j = 0; j < 4; ++j) o[j] = f2b(v[j]);
        *(bf16x4*)&A1[r][c0] = o;    // c0*2 bytes -> 8B aligned
    }
    __syncthreads();  // nidx ready

    // ---- structural self + gather -> A1[:,64:195], A2[:,0:131] ----
    for (int e = t; e < BM * K2; e += THREADS) {
        int r = e / K2;
        int k = e - r * K2;
        int rr = min(r0 + r, n - 1);
        float self = structural[(size_t)rr * K2 + k];
        int n0 = nidx[r * 3 + 0];
        int n1 = nidx[r * 3 + 1];
        int n2 = nidx[r * 3 + 2];
        float v = self + structural[(size_t)n0 * K2 + k]
                       + structural[(size_t)n1 * K2 + k]
                       + structural[(size_t)n2 * K2 + k];
        A1[r][64 + k] = __float2bfloat16(self);
        A2[r][k]      = __float2bfloat16(v * 0.25f);
    }
    __syncthreads();

    // ---- MFMA GEMMs, swapped operands (A=weights, B=nodes) ----
    // 8 waves; wave w owns oc cols [w*32, w*32+32) x all 32 nodes.
    const int wid  = t >> 6;          // 0..7
    const int lane = t & 63;
    const int lr   = lane & 15;
    const int lkc  = lane >> 4;
    const int colBase = wid * 32;

    // ---- GEMM 1: out1 = A1 * WcP^T + bc ----
    {
        f32x4 acc[2][2];  // [ct = oc tile][rt = node tile]
        #pragma unroll
        for (int i = 0; i < 2; ++i)
            #pragma unroll
            for (int j = 0; j < 2; ++j)
                acc[i][j] = (f32x4){0.f, 0.f, 0.f, 0.f};

        #pragma unroll
        for (int ks = 0; ks < K1P; ks += 32) {
            bf16x8 a[2], b[2];
            #pragma unroll
            for (int rt = 0; rt < 2; ++rt)
                a[rt] = *(const bf16x8*)&A1[rt * 16 + lr][ks + lkc * 8];
            #pragma unroll
            for (int ct = 0; ct < 2; ++ct) {
                int oc = colBase + ct * 16 + lr;
                b[ct] = *(const bf16x8*)(WcP + (size_t)oc * K1P + ks + lkc * 8);
            }
            #pragma unroll
            for (int rt = 0; rt < 2; ++rt)
                #pragma unroll
                for (int ct = 0; ct < 2; ++ct)
                    acc[ct][rt] = __builtin_amdgcn_mfma_f32_16x16x32_bf16(b[ct], a[rt], acc[ct][rt], 0, 0, 0);
        }

        #pragma unroll
        for (int ct = 0; ct < 2; ++ct) {
            int oc0 = colBase + ct * 16 + lkc * 4;
            f32x4 b4 = *(const f32x4*)(bc + oc0);
            #pragma unroll
            for (int rt = 0; rt < 2; ++rt) {
                int node = r0 + rt * 16 + lr;
                if (node < n) {
                    f32x4 v = acc[ct][rt] + b4;
                    *(f32x4*)(out1 + (size_t)node * OC + oc0) = v;   // plain store (A/B vs NT)
                }
            }
        }
    }

    // ---- GEMM 2: out2 = A2 * WaP^T + ba ----
    {
        f32x4 acc[2][2];
        #pragma unroll
        for (int i = 0; i < 2; ++i)
            #pragma unroll
            for (int j = 0; j < 2; ++j)
                acc[i][j] = (f32x4){0.f, 0.f, 0.f, 0.f};

        #pragma unroll
        for (int ks = 0; ks < K2P; ks += 32) {
            bf16x8 a[2], b[2];
            #pragma unroll
            for (int rt = 0; rt < 2; ++rt)
                a[rt] = *(const bf16x8*)&A2[rt * 16 + lr][ks + lkc * 8];
            #pragma unroll
            for (int ct = 0; ct < 2; ++ct) {
                int oc = colBase + ct * 16 + lr;
                b[ct] = *(const bf16x8*)(WaP + (size_t)oc * K2P + ks + lkc * 8);
            }
            #pragma unroll
            for (int rt = 0; rt < 2; ++rt)
                #pragma unroll
                for (int ct = 0; ct < 2; ++ct)
                    acc[ct][rt] = __builtin_amdgcn_mfma_f32_16x16x32_bf16(b[ct], a[rt], acc[ct][rt], 0, 0, 0);
        }

        #pragma unroll
        for (int ct = 0; ct < 2; ++ct) {
            int oc0 = colBase + ct * 16 + lkc * 4;
            f32x4 b4 = *(const f32x4*)(ba + oc0);
            #pragma unroll
            for (int rt = 0; rt < 2; ++rt) {
                int node = r0 + rt * 16 + lr;
                if (node < n) {
                    f32x4 v = acc[ct][rt] + b4;
                    *(f32x4*)(out2 + (size_t)node * OC + oc0) = v;   // plain store (A/B vs NT)
                }
            }
        }
    }
}

extern "C" void kernel_launch(void* const* d_in, const int* in_sizes, int n_in,
                              void* d_out, int out_size, void* d_ws, size_t ws_size,
                              hipStream_t stream) {
    const float* spatial    = (const float*)d_in[0];
    const float* structural = (const float*)d_in[1];
    const int*   neighbour  = (const int*)d_in[2];
    const float* Wc = (const float*)d_in[3];
    const float* bc = (const float*)d_in[4];
    const float* Wa = (const float*)d_in[5];
    const float* ba = (const float*)d_in[6];

    const int n = in_sizes[0] / 64;  // 200000

    float* out1 = (float*)d_out;
    float* out2 = out1 + (size_t)n * OC;

    __hip_bfloat16* WcP = (__hip_bfloat16*)d_ws;
    __hip_bfloat16* WaP = WcP + OC * K1P;

    {
        const int total = OC * K1P + OC * K2P;
        prep_weights_v12<<<(total + 255) / 256, 256, 0, stream>>>(Wc, Wa, WcP, WaP);
    }
    {
        const int grid = (n + BM - 1) / BM;  // 6250
        fused_mesh_v12<<<grid, THREADS, 0, stream>>>(spatial, structural, neighbour,
                                                     WcP, bc, WaP, ba, out1, out2, n);
    }
}

// Round 13
// 201.865 us; speedup vs baseline: 1.4112x; 1.4112x over previous
//
#include <hip/hip_runtime.h>
#include <hip/hip_bf16.h>

#define K1 195
#define K1P 224
#define K2 131
#define K2B 136   // structB padded cols: 272 B rows, 16B-aligned
#define K2P 160
#define OC 256
#define BM 32
#define S1 232   // LDS row stride A1 (bf16): 464 B (16B-aligned rows)
#define S2 168   // LDS row stride A2 (bf16): 336 B (16B-aligned rows)
#define THREADS 512

typedef __attribute__((ext_vector_type(4))) float f32x4;
typedef __attribute__((ext_vector_type(8))) short bf16x8;
typedef __attribute__((ext_vector_type(4))) short bf16x4;
typedef __attribute__((ext_vector_type(2))) short bf16x2;

__device__ __forceinline__ short f2b(float x) {
    __hip_bfloat16 h = __float2bfloat16(x);
    return *reinterpret_cast<short*>(&h);
}
__device__ __forceinline__ float b2f(short x) {
    return __uint_as_float(((unsigned)(unsigned short)x) << 16);
}

__global__ void prep_weights_v13(const float* __restrict__ Wc, const float* __restrict__ Wa,
                                 __hip_bfloat16* __restrict__ WcP, __hip_bfloat16* __restrict__ WaP) {
    int t = blockIdx.x * blockDim.x + threadIdx.x;
    const int total1 = OC * K1P;
    const int total2 = OC * K2P;
    if (t < total1) {
        int oc = t / K1P, k = t - oc * K1P;
        float v = (k < K1) ? Wc[oc * K1 + k] : 0.0f;
        WcP[t] = __float2bfloat16(v);
    } else if (t < total1 + total2) {
        int u = t - total1;
        int oc = u / K2P, k = u - oc * K2P;
        float v = (k < K2) ? Wa[oc * K2 + k] : 0.0f;
        WaP[u] = __float2bfloat16(v);
    }
}

// structural [n,131] f32 -> structB [n,136] bf16 (cols 131..135 = 0).
// Pair-wise: thread handles cols (2j, 2j+1) of row r; coalesced 4B stores.
__global__ void prep_structB_v13(const float* __restrict__ structural,
                                 __hip_bfloat16* __restrict__ structB, int n) {
    int idx = blockIdx.x * blockDim.x + threadIdx.x;
    const int ppr = K2B / 2;  // 68 pairs per row
    if (idx >= n * ppr) return;
    int r = idx / ppr;
    int c = (idx - r * ppr) * 2;
    float v0 = (c     < K2) ? structural[(size_t)r * K2 + c]     : 0.0f;
    float v1 = (c + 1 < K2) ? structural[(size_t)r * K2 + c + 1] : 0.0f;
    bf16x2 o;
    o[0] = f2b(v0);
    o[1] = f2b(v1);
    *(bf16x2*)((short*)structB + (size_t)r * K2B + c) = o;  // 4B-aligned
}

template<bool USE_SB>
__global__ __launch_bounds__(THREADS) void fused_mesh_v13(
        const float* __restrict__ spatial,
        const float* __restrict__ structural,
        const __hip_bfloat16* __restrict__ structB,
        const int* __restrict__ neighbour,
        const __hip_bfloat16* __restrict__ WcP,
        const float* __restrict__ bc,
        const __hip_bfloat16* __restrict__ WaP,
        const float* __restrict__ ba,
        float* __restrict__ out1,
        float* __restrict__ out2,
        int n) {
    __shared__ __hip_bfloat16 A1[BM][S1];
    __shared__ __hip_bfloat16 A2[BM][S2];
    __shared__ int nidx[BM * 3];

    const int t = threadIdx.x;
    const int r0 = blockIdx.x * BM;

    // ---- stage neighbour indices ----
    if (t < BM * 3) {
        size_t gi = (size_t)r0 * 3 + t;
        nidx[t] = (gi < (size_t)n * 3) ? neighbour[gi] : 0;
    }

    // ---- zero-pad K tails (195..223 zeros incl. 195-199; benign same-value
    //      overlap with structB copy which also writes zeros there) ----
    for (int e = t; e < BM * (K1P - K1); e += THREADS) {
        int r = e / (K1P - K1);
        int k = K1 + (e - r * (K1P - K1));
        A1[r][k] = __float2bfloat16(0.0f);
    }
    for (int e = t; e < BM * (K2P - K2); e += THREADS) {
        int r = e / (K2P - K2);
        int k = K2 + (e - r * (K2P - K2));
        A2[r][k] = __float2bfloat16(0.0f);
    }

    // ---- spatial -> A1[:, 0:64] : 16 threads/row, 4 floats/thread ----
    {
        int r  = t >> 4;
        int c0 = (t & 15) * 4;
        int rr = min(r0 + r, n - 1);
        f32x4 v = *(const f32x4*)(spatial + (size_t)rr * 64 + c0);
        bf16x4 o;
        #pragma unroll
        for (int j = 0; j < 4; ++j) o[j] = f2b(v[j]);
        *(bf16x4*)&A1[r][c0] = o;
    }
    __syncthreads();  // nidx ready

    if constexpr (USE_SB) {
        // ---- bf16 structB: self copy -> A1[:,64:200); gather avg -> A2[:,0:136) ----
        // 32 rows x 17 chunks of 8 bf16; all 16B-aligned dwordx4 loads.
        for (int u = t; u < BM * 17; u += THREADS) {
            int r = u / 17;
            int c = (u - r * 17) * 8;
            int rr = min(r0 + r, n - 1);
            const short* sb = (const short*)structB;
            bf16x8 vs = *(const bf16x8*)(sb + (size_t)rr * K2B + c);
            *(bf16x8*)&A1[r][64 + c] = vs;   // cols 64..199 (195..199 zeros)
            int n0 = nidx[r * 3 + 0];
            int n1 = nidx[r * 3 + 1];
            int n2 = nidx[r * 3 + 2];
            bf16x8 v0 = *(const bf16x8*)(sb + (size_t)n0 * K2B + c);
            bf16x8 v1 = *(const bf16x8*)(sb + (size_t)n1 * K2B + c);
            bf16x8 v2 = *(const bf16x8*)(sb + (size_t)n2 * K2B + c);
            bf16x8 o;
            #pragma unroll
            for (int j = 0; j < 8; ++j)
                o[j] = f2b((b2f(vs[j]) + b2f(v0[j]) + b2f(v1[j]) + b2f(v2[j])) * 0.25f);
            *(bf16x8*)&A2[r][c] = o;         // cols 0..135 (131..135 zeros)
        }
    } else {
        // ---- fallback: direct f32 path (v11 verbatim) ----
        for (int e = t; e < BM * K2; e += THREADS) {
            int r = e / K2;
            int k = e - r * K2;
            int rr = min(r0 + r, n - 1);
            float self = structural[(size_t)rr * K2 + k];
            int n0 = nidx[r * 3 + 0];
            int n1 = nidx[r * 3 + 1];
            int n2 = nidx[r * 3 + 2];
            float v = self + structural[(size_t)n0 * K2 + k]
                           + structural[(size_t)n1 * K2 + k]
                           + structural[(size_t)n2 * K2 + k];
            A1[r][64 + k] = __float2bfloat16(self);
            A2[r][k]      = __float2bfloat16(v * 0.25f);
        }
    }
    __syncthreads();

    // ---- MFMA GEMMs, swapped operands (A=weights, B=nodes); 8 waves x 32 oc ----
    const int wid  = t >> 6;
    const int lane = t & 63;
    const int lr   = lane & 15;
    const int lkc  = lane >> 4;
    const int colBase = wid * 32;

    // ---- GEMM 1: out1 = A1 * WcP^T + bc ----
    {
        f32x4 acc[2][2];
        #pragma unroll
        for (int i = 0; i < 2; ++i)
            #pragma unroll
            for (int j = 0; j < 2; ++j)
                acc[i][j] = (f32x4){0.f, 0.f, 0.f, 0.f};

        #pragma unroll
        for (int ks = 0; ks < K1P; ks += 32) {
            bf16x8 a[2], b[2];
            #pragma unroll
            for (int rt = 0; rt < 2; ++rt)
                a[rt] = *(const bf16x8*)&A1[rt * 16 + lr][ks + lkc * 8];
            #pragma unroll
            for (int ct = 0; ct < 2; ++ct) {
                int oc = colBase + ct * 16 + lr;
                b[ct] = *(const bf16x8*)(WcP + (size_t)oc * K1P + ks + lkc * 8);
            }
            #pragma unroll
            for (int rt = 0; rt < 2; ++rt)
                #pragma unroll
                for (int ct = 0; ct < 2; ++ct)
                    acc[ct][rt] = __builtin_amdgcn_mfma_f32_16x16x32_bf16(b[ct], a[rt], acc[ct][rt], 0, 0, 0);
        }

        #pragma unroll
        for (int ct = 0; ct < 2; ++ct) {
            int oc0 = colBase + ct * 16 + lkc * 4;
            f32x4 b4 = *(const f32x4*)(bc + oc0);
            #pragma unroll
            for (int rt = 0; rt < 2; ++rt) {
                int node = r0 + rt * 16 + lr;
                if (node < n) {
                    f32x4 v = acc[ct][rt] + b4;
                    __builtin_nontemporal_store(v, (f32x4*)(out1 + (size_t)node * OC + oc0));
                }
            }
        }
    }

    // ---- GEMM 2: out2 = A2 * WaP^T + ba ----
    {
        f32x4 acc[2][2];
        #pragma unroll
        for (int i = 0; i < 2; ++i)
            #pragma unroll
            for (int j = 0; j < 2; ++j)
                acc[i][j] = (f32x4){0.f, 0.f, 0.f, 0.f};

        #pragma unroll
        for (int ks = 0; ks < K2P; ks += 32) {
            bf16x8 a[2], b[2];
            #pragma unroll
            for (int rt = 0; rt < 2; ++rt)
                a[rt] = *(const bf16x8*)&A2[rt * 16 + lr][ks + lkc * 8];
            #pragma unroll
            for (int ct = 0; ct < 2; ++ct) {
                int oc = colBase + ct * 16 + lr;
                b[ct] = *(const bf16x8*)(WaP + (size_t)oc * K2P + ks + lkc * 8);
            }
            #pragma unroll
            for (int rt = 0; rt < 2; ++rt)
                #pragma unroll
                for (int ct = 0; ct < 2; ++ct)
                    acc[ct][rt] = __builtin_amdgcn_mfma_f32_16x16x32_bf16(b[ct], a[rt], acc[ct][rt], 0, 0, 0);
        }

        #pragma unroll
        for (int ct = 0; ct < 2; ++ct) {
            int oc0 = colBase + ct * 16 + lkc * 4;
            f32x4 b4 = *(const f32x4*)(ba + oc0);
            #pragma unroll
            for (int rt = 0; rt < 2; ++rt) {
                int node = r0 + rt * 16 + lr;
                if (node < n) {
                    f32x4 v = acc[ct][rt] + b4;
                    __builtin_nontemporal_store(v, (f32x4*)(out2 + (size_t)node * OC + oc0));
                }
            }
        }
    }
}

extern "C" void kernel_launch(void* const* d_in, const int* in_sizes, int n_in,
                              void* d_out, int out_size, void* d_ws, size_t ws_size,
                              hipStream_t stream) {
    const float* spatial    = (const float*)d_in[0];
    const float* structural = (const float*)d_in[1];
    const int*   neighbour  = (const int*)d_in[2];
    const float* Wc = (const float*)d_in[3];
    const float* bc = (const float*)d_in[4];
    const float* Wa = (const float*)d_in[5];
    const float* ba = (const float*)d_in[6];

    const int n = in_sizes[0] / 64;  // 200000

    float* out1 = (float*)d_out;
    float* out2 = out1 + (size_t)n * OC;

    __hip_bfloat16* WcP = (__hip_bfloat16*)d_ws;
    __hip_bfloat16* WaP = WcP + OC * K1P;

    const size_t wbytes = (size_t)(OC * K1P + OC * K2P) * sizeof(__hip_bfloat16);  // 192 KiB
    const size_t sbytes = (size_t)n * K2B * sizeof(__hip_bfloat16);                // ~54.4 MB
    const bool use_sb = (ws_size >= wbytes + sbytes);
    __hip_bfloat16* structB = (__hip_bfloat16*)((char*)d_ws + wbytes);

    {
        const int total = OC * K1P + OC * K2P;
        prep_weights_v13<<<(total + 255) / 256, 256, 0, stream>>>(Wc, Wa, WcP, WaP);
    }
    const int grid = (n + BM - 1) / BM;  // 6250
    if (use_sb) {
        const int totalp = n * (K2B / 2);
        prep_structB_v13<<<(totalp + 255) / 256, 256, 0, stream>>>(structural, structB, n);
        fused_mesh_v13<true><<<grid, THREADS, 0, stream>>>(spatial, structural, structB, neighbour,
                                                           WcP, bc, WaP, ba, out1, out2, n);
    } else {
        fused_mesh_v13<false><<<grid, THREADS, 0, stream>>>(spatial, structural, structB, neighbour,
                                                            WcP, bc, WaP, ba, out1, out2, n);
    }
}

// Round 14
// 181.777 us; speedup vs baseline: 1.5672x; 1.1105x over previous
//
#include <hip/hip_runtime.h>
#include <hip/hip_bf16.h>

#define K1 195
#define K1P 224
#define K2 131
#define K2P 160
#define OC 256
#define BM 32
#define S1 232   // LDS row stride A1 (bf16): 464 B
#define S2 168   // LDS row stride A2 (bf16): 336 B
#define SO 260   // LDS row stride for f32 output tile (1040 B, +4 float pad)
#define THREADS 512

typedef __attribute__((ext_vector_type(4))) float f32x4;
typedef __attribute__((ext_vector_type(8))) short bf16x8;
typedef __attribute__((ext_vector_type(4))) short bf16x4;

__device__ __forceinline__ short f2b(float x) {
    __hip_bfloat16 h = __float2bfloat16(x);
    return *reinterpret_cast<short*>(&h);
}

__global__ void prep_weights_v14(const float* __restrict__ Wc, const float* __restrict__ Wa,
                                 __hip_bfloat16* __restrict__ WcP, __hip_bfloat16* __restrict__ WaP) {
    int t = blockIdx.x * blockDim.x + threadIdx.x;
    const int total1 = OC * K1P;
    const int total2 = OC * K2P;
    if (t < total1) {
        int oc = t / K1P, k = t - oc * K1P;
        float v = (k < K1) ? Wc[oc * K1 + k] : 0.0f;
        WcP[t] = __float2bfloat16(v);
    } else if (t < total1 + total2) {
        int u = t - total1;
        int oc = u / K2P, k = u - oc * K2P;
        float v = (k < K2) ? Wa[oc * K2 + k] : 0.0f;
        WaP[u] = __float2bfloat16(v);
    }
}

__global__ __launch_bounds__(THREADS) void fused_mesh_v14(
        const float* __restrict__ spatial,
        const float* __restrict__ structural,
        const int* __restrict__ neighbour,
        const __hip_bfloat16* __restrict__ WcP,
        const float* __restrict__ bc,
        const __hip_bfloat16* __restrict__ WaP,
        const float* __restrict__ ba,
        float* __restrict__ out1,
        float* __restrict__ out2,
        int n) {
    // A1/A2/nidx live during staging+GEMM; the SAME memory is then reused as
    // the f32 output tile for the coalesced epilogue.
    __shared__ union SMem {
        struct {
            short A1[BM][S1];
            short A2[BM][S2];
            int   nidx[BM * 3];
        } s;
        float ols[BM][SO];   // 33.3 KB
    } smem;

    const int t = threadIdx.x;
    const int r0 = blockIdx.x * BM;

    // ---- stage neighbour indices ----
    if (t < BM * 3) {
        size_t gi = (size_t)r0 * 3 + t;
        smem.s.nidx[t] = (gi < (size_t)n * 3) ? neighbour[gi] : 0;
    }

    // ---- zero-pad K tails ----
    for (int e = t; e < BM * (K1P - K1); e += THREADS) {
        int r = e / (K1P - K1);
        int k = K1 + (e - r * (K1P - K1));
        smem.s.A1[r][k] = 0;
    }
    for (int e = t; e < BM * (K2P - K2); e += THREADS) {
        int r = e / (K2P - K2);
        int k = K2 + (e - r * (K2P - K2));
        smem.s.A2[r][k] = 0;
    }

    // ---- spatial -> A1[:, 0:64] : 16 threads/row, 4 floats/thread ----
    {
        int r  = t >> 4;              // 0..31
        int c0 = (t & 15) * 4;        // 0,4,..,60
        int rr = min(r0 + r, n - 1);
        f32x4 v = *(const f32x4*)(spatial + (size_t)rr * 64 + c0);
        bf16x4 o;
        #pragma unroll
        for (int j = 0; j < 4; ++j) o[j] = f2b(v[j]);
        *(bf16x4*)&smem.s.A1[r][c0] = o;
    }
    __syncthreads();  // nidx ready

    // ---- structural self + gather -> A1[:,64:195], A2[:,0:131] ----
    for (int e = t; e < BM * K2; e += THREADS) {
        int r = e / K2;
        int k = e - r * K2;
        int rr = min(r0 + r, n - 1);
        float self = structural[(size_t)rr * K2 + k];
        int n0 = smem.s.nidx[r * 3 + 0];
        int n1 = smem.s.nidx[r * 3 + 1];
        int n2 = smem.s.nidx[r * 3 + 2];
        float v = self + structural[(size_t)n0 * K2 + k]
                       + structural[(size_t)n1 * K2 + k]
                       + structural[(size_t)n2 * K2 + k];
        smem.s.A1[r][64 + k] = f2b(self);
        smem.s.A2[r][k]      = f2b(v * 0.25f);
    }
    __syncthreads();

    // ---- MFMA GEMMs, swapped operands (A=weights, B=nodes); 8 waves x 32 oc ----
    const int wid  = t >> 6;
    const int lane = t & 63;
    const int lr   = lane & 15;
    const int lkc  = lane >> 4;
    const int colBase = wid * 32;

    f32x4 acc1[2][2], acc2[2][2];
    #pragma unroll
    for (int i = 0; i < 2; ++i)
        #pragma unroll
        for (int j = 0; j < 2; ++j) {
            acc1[i][j] = (f32x4){0.f, 0.f, 0.f, 0.f};
            acc2[i][j] = (f32x4){0.f, 0.f, 0.f, 0.f};
        }

    // GEMM 1 k-loop
    #pragma unroll
    for (int ks = 0; ks < K1P; ks += 32) {
        bf16x8 a[2], b[2];
        #pragma unroll
        for (int rt = 0; rt < 2; ++rt)
            a[rt] = *(const bf16x8*)&smem.s.A1[rt * 16 + lr][ks + lkc * 8];
        #pragma unroll
        for (int ct = 0; ct < 2; ++ct) {
            int oc = colBase + ct * 16 + lr;
            b[ct] = *(const bf16x8*)(WcP + (size_t)oc * K1P + ks + lkc * 8);
        }
        #pragma unroll
        for (int rt = 0; rt < 2; ++rt)
            #pragma unroll
            for (int ct = 0; ct < 2; ++ct)
                acc1[ct][rt] = __builtin_amdgcn_mfma_f32_16x16x32_bf16(b[ct], a[rt], acc1[ct][rt], 0, 0, 0);
    }

    // GEMM 2 k-loop
    #pragma unroll
    for (int ks = 0; ks < K2P; ks += 32) {
        bf16x8 a[2], b[2];
        #pragma unroll
        for (int rt = 0; rt < 2; ++rt)
            a[rt] = *(const bf16x8*)&smem.s.A2[rt * 16 + lr][ks + lkc * 8];
        #pragma unroll
        for (int ct = 0; ct < 2; ++ct) {
            int oc = colBase + ct * 16 + lr;
            b[ct] = *(const bf16x8*)(WaP + (size_t)oc * K2P + ks + lkc * 8);
        }
        #pragma unroll
        for (int rt = 0; rt < 2; ++rt)
            #pragma unroll
            for (int ct = 0; ct < 2; ++ct)
                acc2[ct][rt] = __builtin_amdgcn_mfma_f32_16x16x32_bf16(b[ct], a[rt], acc2[ct][rt], 0, 0, 0);
    }

    __syncthreads();  // all A1/A2 LDS reads done; safe to overwrite as ols

    // ---- epilogue 1: stage acc1 -> ols, drain rows as 1KB-contiguous NT stores ----
    #pragma unroll
    for (int ct = 0; ct < 2; ++ct) {
        int oc0 = colBase + ct * 16 + lkc * 4;
        f32x4 b4 = *(const f32x4*)(bc + oc0);
        #pragma unroll
        for (int rt = 0; rt < 2; ++rt)
            *(f32x4*)&smem.ols[rt * 16 + lr][oc0] = acc1[ct][rt] + b4;
    }
    __syncthreads();
    #pragma unroll
    for (int i = 0; i < 4; ++i) {
        int row = wid * 4 + i;           // 8 waves x 4 rows = 32
        f32x4 v = *(const f32x4*)&smem.ols[row][lane * 4];
        int node = r0 + row;
        if (node < n)
            __builtin_nontemporal_store(v, (f32x4*)(out1 + (size_t)node * OC + lane * 4));
    }
    __syncthreads();

    // ---- epilogue 2: same for acc2 -> out2 ----
    #pragma unroll
    for (int ct = 0; ct < 2; ++ct) {
        int oc0 = colBase + ct * 16 + lkc * 4;
        f32x4 b4 = *(const f32x4*)(ba + oc0);
        #pragma unroll
        for (int rt = 0; rt < 2; ++rt)
            *(f32x4*)&smem.ols[rt * 16 + lr][oc0] = acc2[ct][rt] + b4;
    }
    __syncthreads();
    #pragma unroll
    for (int i = 0; i < 4; ++i) {
        int row = wid * 4 + i;
        f32x4 v = *(const f32x4*)&smem.ols[row][lane * 4];
        int node = r0 + row;
        if (node < n)
            __builtin_nontemporal_store(v, (f32x4*)(out2 + (size_t)node * OC + lane * 4));
    }
}

extern "C" void kernel_launch(void* const* d_in, const int* in_sizes, int n_in,
                              void* d_out, int out_size, void* d_ws, size_t ws_size,
                              hipStream_t stream) {
    const float* spatial    = (const float*)d_in[0];
    const float* structural = (const float*)d_in[1];
    const int*   neighbour  = (const int*)d_in[2];
    const float* Wc = (const float*)d_in[3];
    const float* bc = (const float*)d_in[4];
    const float* Wa = (const float*)d_in[5];
    const float* ba = (const float*)d_in[6];

    const int n = in_sizes[0] / 64;  // 200000

    float* out1 = (float*)d_out;
    float* out2 = out1 + (size_t)n * OC;

    __hip_bfloat16* WcP = (__hip_bfloat16*)d_ws;
    __hip_bfloat16* WaP = WcP + OC * K1P;

    {
        const int total = OC * K1P + OC * K2P;
        prep_weights_v14<<<(total + 255) / 256, 256, 0, stream>>>(Wc, Wa, WcP, WaP);
    }
    {
        const int grid = (n + BM - 1) / BM;  // 6250
        fused_mesh_v14<<<grid, THREADS, 0, stream>>>(spatial, structural, neighbour,
                                                     WcP, bc, WaP, ba, out1, out2, n);
    }
}